// Round 4
// baseline (6229.168 us; speedup 1.0000x reference)
//
#include <hip/hip_runtime.h>
#include <hip/hip_bf16.h>
#include <math.h>

#define BQ 2
#define SEQ 2048
#define NDIM 1024
#define HEADS 16
#define DH 64
#define NSTEPS 8
#define SCALE 22.60530911f      /* sqrt(511) */
#define SCALE_HEAD 5.567764363f /* sqrt(31)  */
#define INV_SCALE2 (1.0f/511.0f)

typedef unsigned short u16;

__device__ __forceinline__ float bf2f(u16 u) {
  union { unsigned int i; float f; } v; v.i = ((unsigned int)u) << 16; return v.f;
}
__device__ __forceinline__ u16 f2bf(float f) {
  union { float f; unsigned int i; } v; v.f = f;
  unsigned int x = v.i;
  return (u16)((x + 0x7fffu + ((x >> 16) & 1u)) >> 16);
}

// ---------------- dtype probe: flag=1 if input is fp32 (bf16 reinterpretation blows up) ----------------
__global__ void k_flag0(int* flag) { if (threadIdx.x == 0 && blockIdx.x == 0) *flag = 0; }

__global__ __launch_bounds__(256) void k_probe(const u16* __restrict__ x, int* __restrict__ flag) {
  int i = blockIdx.x * 256 + threadIdx.x;   // 65536 probes
  float v = bf2f(x[i]);
  if (!(fabsf(v) <= 1e4f)) atomicOr(flag, 1);   // catches NaN and huge
}

// ---------------- convert input (fp32 or bf16, per flag) -> bf16 ----------------
__global__ __launch_bounds__(256) void k_convert(const void* __restrict__ in, u16* __restrict__ outb,
                                                 const int* __restrict__ flag, int n) {
  int i = blockIdx.x * 256 + threadIdx.x;
  if (i >= n) return;
  if (*flag) outb[i] = f2bf(((const float*)in)[i]);
  else       outb[i] = ((const u16*)in)[i];
}

// ---------------- normalize + scale x -> xs (bf16) ----------------
__global__ __launch_bounds__(256) void k_norm_scale(const u16* __restrict__ x, u16* __restrict__ xs) {
  __shared__ float red[256];
  int row = blockIdx.x;  // b*SEQ + i
  const u16* xr = x + (size_t)row * NDIM;
  u16* orow = xs + (size_t)row * NDIM;
  int t = threadIdx.x;
  float vals[4]; float s = 0.f;
#pragma unroll
  for (int e = 0; e < 4; e++) { float v = bf2f(xr[t + 256*e]); vals[e] = v; s += v*v; }
  red[t] = s; __syncthreads();
  for (int o = 128; o > 0; o >>= 1) { if (t < o) red[t] += red[t+o]; __syncthreads(); }
  float sc = SCALE / fmaxf(sqrtf(red[0]), 1e-12f);
#pragma unroll
  for (int e = 0; e < 4; e++) orow[t + 256*e] = f2bf(vals[e] * sc);
}

// ---------------- generic fp32-accum GEMM: C[m,n] = act(sum_k A[m,k] W[n,k]) (+addsrc) ----------------
template<int OUT_BF16, int GELU, int ADDSRC>
__global__ __launch_bounds__(256) void k_gemm(const u16* __restrict__ A, const u16* __restrict__ W,
                                              float* __restrict__ Cf, u16* __restrict__ Cb,
                                              const u16* __restrict__ addsrc, int M, int N, int K) {
  __shared__ float As[16][68];
  __shared__ float Bs[16][68];
  int bm = blockIdx.x * 64, bn = blockIdx.y * 64;
  int t = threadIdx.x;
  int lr = t >> 2, lc = (t & 3) * 4;
  int tm = (t & 15) * 4, tn = (t >> 4) * 4;
  float acc[4][4] = {};
  const u16* ap = A + (size_t)(bm + lr) * K + lc;
  const u16* wp = W + (size_t)(bn + lr) * K + lc;
  for (int k0 = 0; k0 < K; k0 += 16) {
    ushort4 av = *(const ushort4*)(ap + k0);
    ushort4 wv = *(const ushort4*)(wp + k0);
    As[lc+0][lr] = bf2f(av.x); As[lc+1][lr] = bf2f(av.y);
    As[lc+2][lr] = bf2f(av.z); As[lc+3][lr] = bf2f(av.w);
    Bs[lc+0][lr] = bf2f(wv.x); Bs[lc+1][lr] = bf2f(wv.y);
    Bs[lc+2][lr] = bf2f(wv.z); Bs[lc+3][lr] = bf2f(wv.w);
    __syncthreads();
#pragma unroll
    for (int kk = 0; kk < 16; kk++) {
      float4 a4 = *(const float4*)&As[kk][tm];
      float4 b4 = *(const float4*)&Bs[kk][tn];
      float a[4] = {a4.x, a4.y, a4.z, a4.w};
      float b[4] = {b4.x, b4.y, b4.z, b4.w};
#pragma unroll
      for (int r = 0; r < 4; r++)
#pragma unroll
        for (int c = 0; c < 4; c++) acc[r][c] += a[r]*b[c];
    }
    __syncthreads();
  }
#pragma unroll
  for (int r = 0; r < 4; r++) {
    size_t rowoff = (size_t)(bm + tm + r) * N + bn;
#pragma unroll
    for (int c = 0; c < 4; c++) {
      float v = acc[r][c];
      if (GELU) v = 0.5f * v * (1.0f + erff(v * 0.70710678118f));
      if (ADDSRC) v += bf2f(addsrc[rowoff + tn + c]);
      if (OUT_BF16) Cb[rowoff + tn + c] = f2bf(v);
      else Cf[rowoff + tn + c] = v;
    }
  }
}

// ---------------- per-head normalize q,k (bf16 in) -> [B,H,N,DH] bf16 ----------------
__global__ __launch_bounds__(64) void k_headnorm(const u16* __restrict__ qkraw,
                                                 u16* __restrict__ qn, u16* __restrict__ kn) {
  int blk = blockIdx.x;          // bi*HEADS + h
  int h = blk & (HEADS-1); int bi = blk >> 4;
  int b = bi >> 11, i = bi & (SEQ-1);
  int d = threadIdx.x;
  const u16* base = qkraw + (size_t)bi * (2*NDIM);
  float qv = bf2f(base[h*DH + d]);
  float kv = bf2f(base[NDIM + h*DH + d]);
  float qs = qv*qv, ks = kv*kv;
#pragma unroll
  for (int o = 32; o > 0; o >>= 1) { qs += __shfl_xor(qs, o); ks += __shfl_xor(ks, o); }
  size_t oidx = ((size_t)(b*HEADS + h) * SEQ + i) * DH + d;
  qn[oidx] = f2bf(qv / fmaxf(sqrtf(qs), 1e-12f));
  kn[oidx] = f2bf(kv / fmaxf(sqrtf(ks), 1e-12f));
}

// ---------------- sim + softmax -> attn chunk (bf16), 4 query rows per block ----------------
#define TI 4
__global__ __launch_bounds__(256) void k_attn(const u16* __restrict__ qn, const u16* __restrict__ kn,
                                              u16* __restrict__ attn, int bh0) {
  __shared__ float sim[TI][SEQ];
  __shared__ float qs[TI][DH];
  __shared__ float red[256];
  int bh_local = blockIdx.x >> 9;              // SEQ/TI = 512 blocks per bh
  int bh = bh0 + bh_local;
  int i0 = (blockIdx.x & 511) * TI;
  int t = threadIdx.x;
  { int r = t >> 6, d = t & 63;
    qs[r][d] = bf2f(qn[((size_t)bh * SEQ + i0 + r) * DH + d]); }
  __syncthreads();
  const u16* knb = kn + (size_t)bh * SEQ * DH;
  for (int jt = 0; jt < SEQ/256; jt++) {
    int j = jt*256 + t;
    const u16* kr = knb + (size_t)j * DH;
    float dot[TI] = {0,0,0,0};
#pragma unroll
    for (int c = 0; c < DH/4; c++) {
      ushort4 k4 = *(const ushort4*)(kr + c*4);
      float kx = bf2f(k4.x), ky = bf2f(k4.y), kz = bf2f(k4.z), kw = bf2f(k4.w);
#pragma unroll
      for (int r = 0; r < TI; r++) {
        float4 q4 = *(const float4*)&qs[r][c*4];
        dot[r] += q4.x*kx + q4.y*ky + q4.z*kz + q4.w*kw;
      }
    }
#pragma unroll
    for (int r = 0; r < TI; r++) sim[r][j] = SCALE_HEAD * dot[r];
  }
  __syncthreads();
  for (int r = 0; r < TI; r++) {
    float mx = -1e30f;
    for (int jt = 0; jt < SEQ/256; jt++) mx = fmaxf(mx, sim[r][jt*256+t]);
    red[t] = mx; __syncthreads();
    for (int o = 128; o > 0; o >>= 1) { if (t < o) red[t] = fmaxf(red[t], red[t+o]); __syncthreads(); }
    mx = red[0]; __syncthreads();
    float sum = 0.f;
    for (int jt = 0; jt < SEQ/256; jt++) {
      float e = expf(sim[r][jt*256+t] - mx); sim[r][jt*256+t] = e; sum += e;
    }
    red[t] = sum; __syncthreads();
    for (int o = 128; o > 0; o >>= 1) { if (t < o) red[t] += red[t+o]; __syncthreads(); }
    float inv = 1.0f / red[0]; __syncthreads();
    u16* arow = attn + ((size_t)bh_local * SEQ + i0 + r) * SEQ;
    for (int jt = 0; jt < SEQ/256; jt++) { int j = jt*256+t; arow[j] = f2bf(sim[r][j] * inv); }
  }
}

// ---------------- m0 init ----------------
__global__ void k_minit(float* __restrict__ m, float val, int n) {
  int i = blockIdx.x*256 + threadIdx.x; if (i < n) m[i] = val;
}

// ---------------- zero output fallback (fp32) ----------------
__global__ void k_zero(float* __restrict__ o, int n) {
  int i = blockIdx.x*256 + threadIdx.x; if (i < n) o[i] = 0.f;
}

// ---------------- one mean-field step on a chunk: m_out = mag(xf + attn @ m_in) ----------------
__global__ __launch_bounds__(256) void k_step(const u16* __restrict__ attn, const float* __restrict__ m_in,
                                              const float* __restrict__ xf, float* __restrict__ m_out,
                                              int bh0) {
  __shared__ float m_s[32][64];
  __shared__ float a_s[32][33];
  int bh_local = blockIdx.x >> 6;      // SEQ/32 = 64 tiles per bh
  int bh = bh0 + bh_local;
  int i0 = (blockIdx.x & 63) << 5;
  int b = bh >> 4, h = bh & (HEADS-1);
  int t = threadIdx.x;
  int dg = t & 15;                     // d-group: 4 floats each
  int iw = t >> 4;                     // rows iw and iw+16
  float acc0[4] = {0,0,0,0}, acc1[4] = {0,0,0,0};
  const float* mb = m_in + (size_t)bh * SEQ * DH;
  const u16* ab = attn + ((size_t)bh_local * SEQ + i0) * SEQ;
  for (int j0 = 0; j0 < SEQ; j0 += 32) {
#pragma unroll
    for (int e = 0; e < 8; e++) {
      int idx = t + 256*e; int r = idx >> 6, c = idx & 63;
      m_s[r][c] = mb[(size_t)(j0 + r) * DH + c];
    }
#pragma unroll
    for (int e = 0; e < 4; e++) {
      int idx = t + 256*e; int r = idx >> 5, c = idx & 31;
      a_s[r][c] = bf2f(ab[(size_t)r * SEQ + j0 + c]);
    }
    __syncthreads();
#pragma unroll
    for (int jj = 0; jj < 32; jj++) {
      float4 mv = *(const float4*)&m_s[jj][dg*4];
      float a0 = a_s[iw][jj], a1 = a_s[iw+16][jj];
      acc0[0] += a0*mv.x; acc0[1] += a0*mv.y; acc0[2] += a0*mv.z; acc0[3] += a0*mv.w;
      acc1[0] += a1*mv.x; acc1[1] += a1*mv.y; acc1[2] += a1*mv.z; acc1[3] += a1*mv.w;
    }
    __syncthreads();
  }
  const float* xfb = xf + (size_t)b * SEQ * NDIM + (size_t)h * DH;
  float* mo = m_out + (size_t)bh * SEQ * DH;
#pragma unroll
  for (int half = 0; half < 2; half++) {
    int row = i0 + iw + half*16;
    float* acc = half ? acc1 : acc0;
    float4 x4 = *(const float4*)&xfb[(size_t)row * NDIM + dg*4];
    float t0 = x4.x + acc[0], t1 = x4.y + acc[1], t2 = x4.z + acc[2], t3 = x4.w + acc[3];
    float s = t0*t0 + t1*t1 + t2*t2 + t3*t3;
#pragma unroll
    for (int o = 8; o > 0; o >>= 1) s += __shfl_xor(s, o);   // sum over 16-lane d-group
    float tt = 0.5f*(1.0f + sqrtf(1.0f + s * INV_SCALE2));
    float inv = 1.0f/(2.0f*tt);
    float4 out4 = { t0*inv, t1*inv, t2*inv, t3*inv };
    *(float4*)&mo[(size_t)row * DH + dg*4] = out4;
  }
}

// ---------------- [B,H,N,DH] -> [B,N,H*DH] fp32 output ----------------
__global__ __launch_bounds__(256) void k_out(const float* __restrict__ m, float* __restrict__ out) {
  int idx = blockIdx.x * 256 + threadIdx.x;   // < B*SEQ*NDIM
  int c = idx & (NDIM-1);
  int bi = idx >> 10;
  int b = bi >> 11, i = bi & (SEQ-1);
  int h = c >> 6, d = c & 63;
  out[idx] = m[(((size_t)(b*HEADS + h)) * SEQ + i) * DH + d];
}

extern "C" void kernel_launch(void* const* d_in, const int* in_sizes, int n_in,
                              void* d_out, int out_size, void* d_ws, size_t ws_size,
                              hipStream_t stream) {
  const void* x    = d_in[0];
  const void* w_qk = d_in[1];
  const void* w1   = d_in[2];
  const void* w2   = d_in[3];
  float* out = (float*)d_out;   // reference output dtype is float32

  const size_t E = (size_t)BQ*SEQ*NDIM;         // 4,194,304
  const int NW_QK = 2*NDIM*NDIM;                // 2,097,152
  const int NW1   = 4*NDIM*NDIM;                // 4,194,304
  const int NW2   = 4*NDIM*NDIM;

  char* ws = (char*)d_ws;
  size_t off = 0;
  auto alloc = [&](size_t bytes) { void* p = ws + off; off += (bytes + 255) & ~255ull; return p; };
  int*   flag = (int*) alloc(256);
  u16*   xs = (u16*)  alloc(E*2);               // 8.4 MB, scaled-normalized x (bf16)
  u16*   qb = (u16*)  alloc(E*2);               // 8.4 MB, q normalized [B,H,N,DH]
  u16*   kb = (u16*)  alloc(E*2);               // 8.4 MB
  float* xf = (float*)alloc(E*4);               // 16.8 MB, external field
  float* mA = (float*)alloc(E*4);               // 16.8 MB (early: hosts xb + wqkb)
  float* mB = (float*)alloc(E*4);               // 16.8 MB (early: hosts w1b + w2b)

  // converted-input aliases (dead before mA/mB are first written)
  u16* xb   = (u16*)mA;                          // 8.4 MB, dead after k_norm_scale
  u16* wqkb = (u16*)((char*)mA + E*2);           // 4.2 MB, dead after qk GEMM
  u16* w1b  = (u16*)mB;                          // 8.4 MB, dead after FFN
  u16* w2b  = (u16*)((char*)mB + (size_t)NW1*2); // 8.4 MB, dead after FFN

  // scratch region S: qkraw (16.8MB) -> hbuf chunk (8.4MB) -> attn chunk (CH*8.4MB)
  const size_t QKRAW_B = E*2*2;                 // [4096, 2048] bf16
  const size_t ATT1_B  = (size_t)SEQ*SEQ*2;     // one head's attn, 8.4 MB
  size_t avail = (ws_size > off) ? ws_size - off : 0;
  int CH = 0;
  const int cands[6] = {32,16,8,4,2,1};
  for (int ci = 0; ci < 6; ci++) {
    size_t need = (size_t)cands[ci]*ATT1_B; if (need < QKRAW_B) need = QKRAW_B;
    if (need <= avail) { CH = cands[ci]; break; }
  }
  if (CH == 0) {  // workspace too small even for minimal plan: zeros (diagnostic signature)
    k_zero<<<(out_size+255)/256, 256, 0, stream>>>(out, out_size);
    return;
  }
  u16* qkraw = (u16*)(ws + off);
  u16* hbuf  = (u16*)(ws + off);
  u16* attn  = (u16*)(ws + off);

  const int M = BQ*SEQ;  // 4096

  // dtype probe + canonical bf16 conversion of all inputs
  k_flag0<<<1, 64, 0, stream>>>(flag);
  k_probe<<<256, 256, 0, stream>>>((const u16*)x, flag);
  k_convert<<<(int)(E/256), 256, 0, stream>>>(x, xb, flag, (int)E);
  k_convert<<<NW_QK/256, 256, 0, stream>>>(w_qk, wqkb, flag, NW_QK);
  k_convert<<<NW1/256, 256, 0, stream>>>(w1, w1b, flag, NW1);
  k_convert<<<NW2/256, 256, 0, stream>>>(w2, w2b, flag, NW2);

  k_norm_scale<<<M, 256, 0, stream>>>(xb, xs);
  { dim3 g(M/64, 2048/64); k_gemm<1,0,0><<<g, 256, 0, stream>>>(xs, wqkb, nullptr, qkraw, nullptr, M, 2048, 1024); }
  k_headnorm<<<M*HEADS, 64, 0, stream>>>(qkraw, qb, kb);
  // FFN in 1024-row chunks (hbuf = 1024 x 4096 bf16, aliases qkraw which is now dead)
  for (int c = 0; c < 4; c++) {
    const u16* xsc = xs + (size_t)c*1024*NDIM;
    { dim3 g(1024/64, 4096/64); k_gemm<1,1,0><<<g, 256, 0, stream>>>(xsc, w1b, nullptr, hbuf, nullptr, 1024, 4096, 1024); }
    { dim3 g(1024/64, 1024/64); k_gemm<0,0,1><<<g, 256, 0, stream>>>(hbuf, w2b, xf + (size_t)c*1024*NDIM, nullptr, xsc, 1024, 1024, 4096); }
  }

  float t0 = 0.5f*(1.0f + sqrtf(1.0f + 64.0f/511.0f));
  float m0val = 1.0f/(2.0f*t0);
  k_minit<<<(int)(E/256), 256, 0, stream>>>(mA, m0val, (int)E);

  // per-head-chunk: materialize attn for CH (b,h) pairs, run the 8 MF steps on that chunk
  for (int c0 = 0; c0 < BQ*HEADS; c0 += CH) {
    k_attn<<<CH*(SEQ/TI), 256, 0, stream>>>(qb, kb, attn, c0);
    float* src = mA; float* dst = mB;
    for (int s = 0; s < NSTEPS; s++) {
      k_step<<<CH*(SEQ/32), 256, 0, stream>>>(attn, src, xf, dst, c0);
      float* tmp = src; src = dst; dst = tmp;
    }
  }
  // NSTEPS even -> final m is in mA for every chunk
  k_out<<<(int)(E/256), 256, 0, stream>>>(mA, out);
}

// Round 5
// 1150.809 us; speedup vs baseline: 5.4129x; 5.4129x over previous
//
#include <hip/hip_runtime.h>
#include <hip/hip_bf16.h>
#include <math.h>

#define BQ 2
#define SEQ 2048
#define NDIM 1024
#define HEADS 16
#define DH 64
#define NSTEPS 8
#define SCALE 22.60530911f      /* sqrt(511) */
#define SCALE_HEAD 5.567764363f /* sqrt(31)  */
#define INV_SCALE2 (1.0f/511.0f)

typedef unsigned short u16;
typedef __attribute__((ext_vector_type(8))) short bf16x8;   // 8 bf16 = 4 VGPR
typedef __attribute__((ext_vector_type(4))) float floatx4;  // MFMA 16x16 acc

__device__ __forceinline__ float bf2f(u16 u) {
  union { unsigned int i; float f; } v; v.i = ((unsigned int)u) << 16; return v.f;
}
__device__ __forceinline__ u16 f2bf(float f) {
  union { float f; unsigned int i; } v; v.f = f;
  unsigned int x = v.i;
  return (u16)((x + 0x7fffu + ((x >> 16) & 1u)) >> 16);
}

// async global->LDS, 16B per lane; LDS dest = wave-uniform base + lane*16
#define GLD16(gp, lp) __builtin_amdgcn_global_load_lds( \
    (__attribute__((address_space(1))) void*)(gp),      \
    (__attribute__((address_space(3))) void*)(lp), 16, 0, 0)

// ---------------- dtype probe: flag=1 if input is fp32 ----------------
__global__ void k_flag0(int* flag) { if (threadIdx.x == 0 && blockIdx.x == 0) *flag = 0; }

__global__ __launch_bounds__(256) void k_probe(const u16* __restrict__ x, int* __restrict__ flag) {
  int i = blockIdx.x * 256 + threadIdx.x;
  float v = bf2f(x[i]);
  if (!(fabsf(v) <= 1e4f)) atomicOr(flag, 1);
}

__global__ __launch_bounds__(256) void k_convert(const void* __restrict__ in, u16* __restrict__ outb,
                                                 const int* __restrict__ flag, int n) {
  int i = blockIdx.x * 256 + threadIdx.x;
  if (i >= n) return;
  if (*flag) outb[i] = f2bf(((const float*)in)[i]);
  else       outb[i] = ((const u16*)in)[i];
}

// ---------------- normalize + scale x -> xs (bf16) ----------------
__global__ __launch_bounds__(256) void k_norm_scale(const u16* __restrict__ x, u16* __restrict__ xs) {
  __shared__ float red[256];
  int row = blockIdx.x;
  const u16* xr = x + (size_t)row * NDIM;
  u16* orow = xs + (size_t)row * NDIM;
  int t = threadIdx.x;
  float vals[4]; float s = 0.f;
#pragma unroll
  for (int e = 0; e < 4; e++) { float v = bf2f(xr[t + 256*e]); vals[e] = v; s += v*v; }
  red[t] = s; __syncthreads();
  for (int o = 128; o > 0; o >>= 1) { if (t < o) red[t] += red[t+o]; __syncthreads(); }
  float sc = SCALE / fmaxf(sqrtf(red[0]), 1e-12f);
#pragma unroll
  for (int e = 0; e < 4; e++) orow[t + 256*e] = f2bf(vals[e] * sc);
}

// ---------------- MFMA GEMM: C[m,n] = act(sum_k A[m,k] W[n,k]) (+addsrc) ----------------
// 128x128 tile, BK=32, 4 waves in 2x2, each wave 4x4 MFMA tiles of 16x16x32.
template<int OUT_BF16, int GELU, int ADDSRC>
__global__ __launch_bounds__(256) void k_gemm(const u16* __restrict__ A, const u16* __restrict__ W,
                                              float* __restrict__ Cf, u16* __restrict__ Cb,
                                              const u16* __restrict__ addsrc, int M, int N, int K) {
  __shared__ __align__(16) u16 As[128*32];
  __shared__ __align__(16) u16 Bs[128*32];
  int t = threadIdx.x;
  int w = t >> 6, L = t & 63;
  int quad = L >> 4, l15 = L & 15;
  int wr = w >> 1, wc = w & 1;
  int bm = blockIdx.x * 128, bn = blockIdx.y * 128;
  int srow = L >> 2, scol = (L & 3) * 8;
  floatx4 acc[4][4];
#pragma unroll
  for (int i = 0; i < 4; i++)
#pragma unroll
    for (int j = 0; j < 4; j++) acc[i][j] = (floatx4){0.f,0.f,0.f,0.f};

  for (int k0 = 0; k0 < K; k0 += 32) {
#pragma unroll
    for (int c = 0; c < 2; c++) {
      int r = c*64 + w*16 + srow;
      GLD16(A + (size_t)(bm + r)*K + k0 + scol, &As[(c*64 + w*16)*32]);
      GLD16(W + (size_t)(bn + r)*K + k0 + scol, &Bs[(c*64 + w*16)*32]);
    }
    __syncthreads();
    bf16x8 af[4], bfr[4];
#pragma unroll
    for (int mt = 0; mt < 4; mt++) af[mt]  = *(const bf16x8*)&As[(wr*64 + mt*16 + l15)*32 + quad*8];
#pragma unroll
    for (int nt = 0; nt < 4; nt++) bfr[nt] = *(const bf16x8*)&Bs[(wc*64 + nt*16 + l15)*32 + quad*8];
#pragma unroll
    for (int mt = 0; mt < 4; mt++)
#pragma unroll
      for (int nt = 0; nt < 4; nt++)
        acc[mt][nt] = __builtin_amdgcn_mfma_f32_16x16x32_bf16(af[mt], bfr[nt], acc[mt][nt], 0, 0, 0);
    __syncthreads();
  }
#pragma unroll
  for (int mt = 0; mt < 4; mt++)
#pragma unroll
    for (int reg = 0; reg < 4; reg++) {
      int m = bm + wr*64 + mt*16 + quad*4 + reg;
      size_t rowoff = (size_t)m * N;
#pragma unroll
      for (int nt = 0; nt < 4; nt++) {
        int n = bn + wc*64 + nt*16 + l15;
        float v = acc[mt][nt][reg];
        if (GELU) v = 0.5f * v * (1.0f + erff(v * 0.70710678118f));
        if (ADDSRC) v += bf2f(addsrc[rowoff + n]);
        if (OUT_BF16) Cb[rowoff + n] = f2bf(v);
        else Cf[rowoff + n] = v;
      }
    }
}

// ---------------- per-head normalize q,k -> [B,H,N,DH] bf16 ----------------
__global__ __launch_bounds__(64) void k_headnorm(const u16* __restrict__ qkraw,
                                                 u16* __restrict__ qn, u16* __restrict__ kn) {
  int blk = blockIdx.x;
  int h = blk & (HEADS-1); int bi = blk >> 4;
  int b = bi >> 11, i = bi & (SEQ-1);
  int d = threadIdx.x;
  const u16* base = qkraw + (size_t)bi * (2*NDIM);
  float qv = bf2f(base[h*DH + d]);
  float kv = bf2f(base[NDIM + h*DH + d]);
  float qs = qv*qv, ks = kv*kv;
#pragma unroll
  for (int o = 32; o > 0; o >>= 1) { qs += __shfl_xor(qs, o); ks += __shfl_xor(ks, o); }
  size_t oidx = ((size_t)(b*HEADS + h) * SEQ + i) * DH + d;
  qn[oidx] = f2bf(qv / fmaxf(sqrtf(qs), 1e-12f));
  kn[oidx] = f2bf(kv / fmaxf(sqrtf(ks), 1e-12f));
}

// ---------------- MFMA attn: 16 q-rows per block, acc-resident 2048-col scores + fused softmax ----------------
__global__ __launch_bounds__(256) void k_attn(const u16* __restrict__ qb, const u16* __restrict__ kb,
                                              u16* __restrict__ attn, int bh0) {
  __shared__ float redbuf[2][4][16];
  int t = threadIdx.x;
  int w = t >> 6, L = t & 63;
  int quad = L >> 4, l15 = L & 15;
  int bh_local = blockIdx.x >> 7;            // 128 i-tiles per bh
  int bh = bh0 + bh_local;
  int i0 = (blockIdx.x & 127) * 16;
  const u16* qrow = qb + ((size_t)bh*SEQ + i0 + l15)*DH + quad*8;
  bf16x8 a0 = *(const bf16x8*)qrow;
  bf16x8 a1 = *(const bf16x8*)(qrow + 32);
  const u16* kbase = kb + (size_t)bh*SEQ*DH;
  floatx4 acc[32];
#pragma unroll
  for (int tt = 0; tt < 32; tt++) {
    int j = w*512 + tt*16 + l15;
    const u16* krow = kbase + (size_t)j*DH + quad*8;
    bf16x8 b0 = *(const bf16x8*)krow;
    bf16x8 b1 = *(const bf16x8*)(krow + 32);
    floatx4 c = (floatx4){0.f,0.f,0.f,0.f};
    c = __builtin_amdgcn_mfma_f32_16x16x32_bf16(a0, b0, c, 0, 0, 0);
    c = __builtin_amdgcn_mfma_f32_16x16x32_bf16(a1, b1, c, 0, 0, 0);
    acc[tt] = c;
  }
  float mx[4] = {-3.0e38f, -3.0e38f, -3.0e38f, -3.0e38f};
#pragma unroll
  for (int tt = 0; tt < 32; tt++)
#pragma unroll
    for (int r = 0; r < 4; r++) mx[r] = fmaxf(mx[r], acc[tt][r]);
#pragma unroll
  for (int r = 0; r < 4; r++) {
    mx[r] = fmaxf(mx[r], __shfl_xor(mx[r], 1));
    mx[r] = fmaxf(mx[r], __shfl_xor(mx[r], 2));
    mx[r] = fmaxf(mx[r], __shfl_xor(mx[r], 4));
    mx[r] = fmaxf(mx[r], __shfl_xor(mx[r], 8));
  }
  if (l15 == 0) {
#pragma unroll
    for (int r = 0; r < 4; r++) redbuf[0][w][quad*4 + r] = mx[r];
  }
  __syncthreads();
  float gmx[4], sm[4];
#pragma unroll
  for (int r = 0; r < 4; r++) {
    gmx[r] = fmaxf(fmaxf(redbuf[0][0][quad*4+r], redbuf[0][1][quad*4+r]),
                   fmaxf(redbuf[0][2][quad*4+r], redbuf[0][3][quad*4+r]));
    sm[r] = 0.f;
  }
#pragma unroll
  for (int tt = 0; tt < 32; tt++)
#pragma unroll
    for (int r = 0; r < 4; r++) {
      float e = expf(SCALE_HEAD * (acc[tt][r] - gmx[r]));
      acc[tt][r] = e; sm[r] += e;
    }
#pragma unroll
  for (int r = 0; r < 4; r++) {
    sm[r] += __shfl_xor(sm[r], 1);
    sm[r] += __shfl_xor(sm[r], 2);
    sm[r] += __shfl_xor(sm[r], 4);
    sm[r] += __shfl_xor(sm[r], 8);
  }
  if (l15 == 0) {
#pragma unroll
    for (int r = 0; r < 4; r++) redbuf[1][w][quad*4 + r] = sm[r];
  }
  __syncthreads();
  float inv[4];
#pragma unroll
  for (int r = 0; r < 4; r++)
    inv[r] = 1.0f / (redbuf[1][0][quad*4+r] + redbuf[1][1][quad*4+r] +
                     redbuf[1][2][quad*4+r] + redbuf[1][3][quad*4+r]);
  u16* abase = attn + ((size_t)bh_local*SEQ + i0)*SEQ;
#pragma unroll
  for (int tt = 0; tt < 32; tt++) {
    int j = w*512 + tt*16 + l15;
#pragma unroll
    for (int r = 0; r < 4; r++)
      abase[(size_t)(quad*4 + r)*SEQ + j] = f2bf(acc[tt][r] * inv[r]);
  }
}

// ---------------- m0 init (bf16 constant) ----------------
__global__ void k_minit_bf(u16* __restrict__ m, u16 val, int n) {
  int i = blockIdx.x*256 + threadIdx.x; if (i < n) m[i] = val;
}

__global__ void k_zero(float* __restrict__ o, int n) {
  int i = blockIdx.x*256 + threadIdx.x; if (i < n) o[i] = 0.f;
}

// ---------------- MFMA mean-field step: m_out = mag(xf + attn @ m_in) ----------------
// m stored transposed [bh][d][i] bf16. Block: 128 i-rows x all 64 d. LAST writes fp32 out [b,i,dim].
template<int LAST>
__global__ __launch_bounds__(256) void k_step(const u16* __restrict__ attn, const u16* __restrict__ mT_in,
                                              const float* __restrict__ xf, u16* __restrict__ mT_out,
                                              float* __restrict__ out, int bh0) {
  __shared__ __align__(16) u16 As[128*32];
  __shared__ __align__(16) u16 Bs[64*32];
  int t = threadIdx.x;
  int w = t >> 6, L = t & 63;
  int quad = L >> 4, l15 = L & 15;
  int bh_local = blockIdx.x >> 4;            // 16 i-tiles per bh
  int bh = bh0 + bh_local;
  int i0 = (blockIdx.x & 15) * 128;
  int b = bh >> 4, h = bh & (HEADS-1);
  int srow = L >> 2, scol = (L & 3) * 8;
  const u16* abase = attn + (size_t)bh_local*SEQ*SEQ;
  const u16* mbase = mT_in + (size_t)bh*DH*SEQ;
  floatx4 acc[2][4];
#pragma unroll
  for (int i = 0; i < 2; i++)
#pragma unroll
    for (int j = 0; j < 4; j++) acc[i][j] = (floatx4){0.f,0.f,0.f,0.f};

  for (int j0 = 0; j0 < SEQ; j0 += 32) {
#pragma unroll
    for (int c = 0; c < 2; c++) {
      int r = c*64 + w*16 + srow;
      GLD16(abase + (size_t)(i0 + r)*SEQ + j0 + scol, &As[(c*64 + w*16)*32]);
    }
    {
      int d = w*16 + srow;
      GLD16(mbase + (size_t)d*SEQ + j0 + scol, &Bs[(w*16)*32]);
    }
    __syncthreads();
    bf16x8 af[2], bfr[4];
#pragma unroll
    for (int mt = 0; mt < 2; mt++) af[mt]  = *(const bf16x8*)&As[(w*32 + mt*16 + l15)*32 + quad*8];
#pragma unroll
    for (int nt = 0; nt < 4; nt++) bfr[nt] = *(const bf16x8*)&Bs[(nt*16 + l15)*32 + quad*8];
#pragma unroll
    for (int mt = 0; mt < 2; mt++)
#pragma unroll
      for (int nt = 0; nt < 4; nt++)
        acc[mt][nt] = __builtin_amdgcn_mfma_f32_16x16x32_bf16(af[mt], bfr[nt], acc[mt][nt], 0, 0, 0);
    __syncthreads();
  }
#pragma unroll
  for (int mt = 0; mt < 2; mt++) {
    int ibase = i0 + w*32 + mt*16 + quad*4;
    float th[4][4]; float invr[4];
#pragma unroll
    for (int reg = 0; reg < 4; reg++) {
      size_t xoff = ((size_t)b*SEQ + ibase + reg)*NDIM + h*DH + l15;
      float s = 0.f;
#pragma unroll
      for (int nt = 0; nt < 4; nt++) {
        float v = acc[mt][nt][reg] + xf[xoff + nt*16];
        th[nt][reg] = v; s += v*v;
      }
      s += __shfl_xor(s, 1); s += __shfl_xor(s, 2); s += __shfl_xor(s, 4); s += __shfl_xor(s, 8);
      float tt2 = 0.5f*(1.0f + sqrtf(1.0f + s * INV_SCALE2));
      invr[reg] = 1.0f/(2.0f*tt2);
    }
    if (LAST) {
#pragma unroll
      for (int reg = 0; reg < 4; reg++) {
        size_t ooff = ((size_t)b*SEQ + ibase + reg)*NDIM + h*DH + l15;
#pragma unroll
        for (int nt = 0; nt < 4; nt++) out[ooff + nt*16] = th[nt][reg]*invr[reg];
      }
    } else {
#pragma unroll
      for (int nt = 0; nt < 4; nt++) {
        ushort4 o;
        o.x = f2bf(th[nt][0]*invr[0]);
        o.y = f2bf(th[nt][1]*invr[1]);
        o.z = f2bf(th[nt][2]*invr[2]);
        o.w = f2bf(th[nt][3]*invr[3]);
        *(ushort4*)&mT_out[((size_t)bh*DH + nt*16 + l15)*SEQ + ibase] = o;
      }
    }
  }
}

extern "C" void kernel_launch(void* const* d_in, const int* in_sizes, int n_in,
                              void* d_out, int out_size, void* d_ws, size_t ws_size,
                              hipStream_t stream) {
  const void* x    = d_in[0];
  const void* w_qk = d_in[1];
  const void* w1   = d_in[2];
  const void* w2   = d_in[3];
  float* out = (float*)d_out;

  const size_t E = (size_t)BQ*SEQ*NDIM;     // 4,194,304
  const int NW_QK = 2*NDIM*NDIM;
  const int NW1   = 4*NDIM*NDIM;
  const int NW2   = 4*NDIM*NDIM;

  char* ws = (char*)d_ws;
  size_t off = 0;
  auto alloc = [&](size_t bytes) { void* p = ws + off; off += (bytes + 255) & ~255ull; return p; };
  int*  flag = (int*)alloc(256);
  u16*  xs  = (u16*)alloc(E*2);             // scaled-normalized x
  u16*  qb  = (u16*)alloc(E*2);             // q normalized [B,H,N,DH]
  u16*  kb  = (u16*)alloc(E*2);
  float* xf = (float*)alloc(E*4);           // external field fp32
  u16*  mTa = (u16*)alloc(E*2);             // m transposed [B,H,DH,N] bf16
  u16*  mTb = (u16*)alloc(E*2);

  char* S = ws + off;
  size_t availS = (ws_size > off) ? ws_size - off : 0;
  // S-region temporal plan: [wqkb|qkraw] -> [.|.|w1b|w2b|hbuf] -> [attn chunk]
  u16* wqkb  = (u16*)(S);
  u16* qkraw = (u16*)(S + 4194304);
  u16* w1b   = (u16*)(S + 20971520);
  u16* w2b   = (u16*)(S + 29360128);
  u16* hbuf  = (u16*)(S + 37748736);
  u16* attn  = (u16*)(S);
  u16* xb    = mTa;                          // alias: dead before k_minit_bf

  const int rcs[6] = {4096, 2048, 1024, 512, 256, 128};
  int RC = 0;
  for (int i = 0; i < 6; i++)
    if (37748736ull + (size_t)rcs[i]*4096*2 <= availS) { RC = rcs[i]; break; }
  const int chs[6] = {32, 16, 8, 4, 2, 1};
  int CH = 0;
  for (int i = 0; i < 6; i++)
    if ((size_t)chs[i]*SEQ*SEQ*2 <= availS) { CH = chs[i]; break; }
  if (RC == 0 || CH == 0) {
    k_zero<<<(out_size+255)/256, 256, 0, stream>>>(out, out_size);
    return;
  }

  const int M = BQ*SEQ;  // 4096

  // dtype probe + canonical bf16 conversion
  k_flag0<<<1, 64, 0, stream>>>(flag);
  k_probe<<<256, 256, 0, stream>>>((const u16*)x, flag);
  k_convert<<<(int)(E/256), 256, 0, stream>>>(x, xb, flag, (int)E);
  k_convert<<<NW_QK/256, 256, 0, stream>>>(w_qk, wqkb, flag, NW_QK);
  k_convert<<<NW1/256, 256, 0, stream>>>(w1, w1b, flag, NW1);
  k_convert<<<NW2/256, 256, 0, stream>>>(w2, w2b, flag, NW2);

  k_norm_scale<<<M, 256, 0, stream>>>(xb, xs);
  { dim3 g(M/128, 2048/128); k_gemm<1,0,0><<<g, 256, 0, stream>>>(xs, wqkb, nullptr, qkraw, nullptr, M, 2048, 1024); }
  k_headnorm<<<M*HEADS, 64, 0, stream>>>(qkraw, qb, kb);

  for (int c = 0; c < M/RC; c++) {
    const u16* xsc = xs + (size_t)c*RC*NDIM;
    { dim3 g(RC/128, 4096/128); k_gemm<1,1,0><<<g, 256, 0, stream>>>(xsc, w1b, nullptr, hbuf, nullptr, RC, 4096, 1024); }
    { dim3 g(RC/128, 1024/128); k_gemm<0,0,1><<<g, 256, 0, stream>>>(hbuf, w2b, xf + (size_t)c*RC*NDIM, nullptr, xsc, RC, 1024, 4096); }
  }

  float t0 = 0.5f*(1.0f + sqrtf(1.0f + 64.0f/511.0f));
  float m0val = 1.0f/(2.0f*t0);
  union { float f; unsigned int i; } mv; mv.f = m0val;
  u16 m0bf = (u16)((mv.i + 0x7fffu + ((mv.i >> 16) & 1u)) >> 16);
  k_minit_bf<<<(int)(E/256), 256, 0, stream>>>(mTa, m0bf, (int)E);

  for (int c0 = 0; c0 < BQ*HEADS; c0 += CH) {
    k_attn<<<CH*128, 256, 0, stream>>>(qb, kb, attn, c0);
    for (int s = 0; s < NSTEPS; s++) {
      u16* src = (s & 1) ? mTb : mTa;
      u16* dst = (s & 1) ? mTa : mTb;
      if (s == NSTEPS-1)
        k_step<1><<<CH*16, 256, 0, stream>>>(attn, src, xf, nullptr, out, c0);
      else
        k_step<0><<<CH*16, 256, 0, stream>>>(attn, src, xf, dst, nullptr, c0);
    }
  }
}

// Round 7
// 868.435 us; speedup vs baseline: 7.1729x; 1.3252x over previous
//
#include <hip/hip_runtime.h>
#include <hip/hip_bf16.h>
#include <math.h>

#define BQ 2
#define SEQ 2048
#define NDIM 1024
#define HEADS 16
#define DH 64
#define NSTEPS 8
#define SCALE 22.60530911f      /* sqrt(511) */
#define SCALE_HEAD 5.567764363f /* sqrt(31)  */
#define INV_SCALE2 (1.0f/511.0f)
#define EXS 8.0325527f          /* SCALE_HEAD * log2(e) */

typedef unsigned short u16;
typedef unsigned char u8;
typedef long long i64;
typedef __attribute__((ext_vector_type(8))) short bf16x8;   // 8 bf16 = 4 VGPR
typedef __attribute__((ext_vector_type(4))) float floatx4;  // MFMA 16x16 acc

__device__ __forceinline__ float bf2f(u16 u) {
  union { unsigned int i; float f; } v; v.i = ((unsigned int)u) << 16; return v.f;
}
__device__ __forceinline__ u16 f2bf(float f) {
  union { float f; unsigned int i; } v; v.f = f;
  unsigned int x = v.i;
  return (u16)((x + 0x7fffu + ((x >> 16) & 1u)) >> 16);
}

// manual OCP e4m3fn encode, RNE; saturate +-448; NaN/Inf -> +-448; subnormals to 2^-9
__device__ __forceinline__ unsigned f2e4m3(float x) {
  union { float f; unsigned u; } v; v.f = x;
  unsigned sign = (v.u >> 24) & 0x80u;
  float ax = fabsf(x);
  if (ax < 0.015625f) {                      // subnormal range, step 2^-9
    int q = (int)rintf(ax * 512.0f);         // 0..8 (8 rounds up to min normal)
    return sign | (unsigned)q;
  }
  if (!(ax < 448.0f)) return sign | 0x7Eu;   // clamp; catches NaN/Inf too
  unsigned bits = v.u & 0x7FFFFFFFu;
  bits += 0x0007FFFFu + ((bits >> 20) & 1u); // RNE to 3-bit mantissa
  unsigned e = (bits >> 23) - 120u;          // rebias 127 -> 7
  unsigned m = (bits >> 20) & 7u;
  if (e >= 16u) return sign | 0x7Eu;
  return sign | (e << 3) | m;
}
__device__ __forceinline__ int pk4_e4m3(float a, float b, float c, float d) {
  return (int)(f2e4m3(a) | (f2e4m3(b) << 8) | (f2e4m3(c) << 16) | (f2e4m3(d) << 24));
}

// async global->LDS, 16B per lane; LDS dest = wave-uniform base + lane*16
#define GLD16(gp, lp) __builtin_amdgcn_global_load_lds( \
    (__attribute__((address_space(1))) void*)(gp),      \
    (__attribute__((address_space(3))) void*)(lp), 16, 0, 0)

// ---------------- dtype probe: flag=1 if input is fp32 ----------------
__global__ void k_flag0(int* flag) { if (threadIdx.x == 0 && blockIdx.x == 0) *flag = 0; }

__global__ __launch_bounds__(256) void k_probe(const u16* __restrict__ x, int* __restrict__ flag) {
  int i = blockIdx.x * 256 + threadIdx.x;
  float v = bf2f(x[i]);
  if (!(fabsf(v) <= 1e4f)) atomicOr(flag, 1);
}

__global__ __launch_bounds__(256) void k_convert(const void* __restrict__ in, u16* __restrict__ outb,
                                                 const int* __restrict__ flag, int n) {
  int i = blockIdx.x * 256 + threadIdx.x;
  if (i >= n) return;
  if (*flag) outb[i] = f2bf(((const float*)in)[i]);
  else       outb[i] = ((const u16*)in)[i];
}

// ---------------- normalize + scale x -> xs (bf16) ----------------
__global__ __launch_bounds__(256) void k_norm_scale(const u16* __restrict__ x, u16* __restrict__ xs) {
  __shared__ float red[256];
  int row = blockIdx.x;
  const u16* xr = x + (size_t)row * NDIM;
  u16* orow = xs + (size_t)row * NDIM;
  int t = threadIdx.x;
  float vals[4]; float s = 0.f;
#pragma unroll
  for (int e = 0; e < 4; e++) { float v = bf2f(xr[t + 256*e]); vals[e] = v; s += v*v; }
  red[t] = s; __syncthreads();
  for (int o = 128; o > 0; o >>= 1) { if (t < o) red[t] += red[t+o]; __syncthreads(); }
  float sc = SCALE / fmaxf(sqrtf(red[0]), 1e-12f);
#pragma unroll
  for (int e = 0; e < 4; e++) orow[t + 256*e] = f2bf(vals[e] * sc);
}

// ---------------- MFMA GEMM (bf16): C[m,n] = act(sum_k A[m,k] W[n,k]) (+addsrc) ----------------
template<int OUT_BF16, int GELU, int ADDSRC>
__global__ __launch_bounds__(256) void k_gemm(const u16* __restrict__ A, const u16* __restrict__ W,
                                              float* __restrict__ Cf, u16* __restrict__ Cb,
                                              const u16* __restrict__ addsrc, int M, int N, int K) {
  __shared__ __align__(16) u16 As[128*32];
  __shared__ __align__(16) u16 Bs[128*32];
  int t = threadIdx.x;
  int w = t >> 6, L = t & 63;
  int quad = L >> 4, l15 = L & 15;
  int wr = w >> 1, wc = w & 1;
  int bm = blockIdx.x * 128, bn = blockIdx.y * 128;
  int srow = L >> 2, scol = (L & 3) * 8;
  floatx4 acc[4][4];
#pragma unroll
  for (int i = 0; i < 4; i++)
#pragma unroll
    for (int j = 0; j < 4; j++) acc[i][j] = (floatx4){0.f,0.f,0.f,0.f};

  for (int k0 = 0; k0 < K; k0 += 32) {
#pragma unroll
    for (int c = 0; c < 2; c++) {
      int r = c*64 + w*16 + srow;
      GLD16(A + (size_t)(bm + r)*K + k0 + scol, &As[(c*64 + w*16)*32]);
      GLD16(W + (size_t)(bn + r)*K + k0 + scol, &Bs[(c*64 + w*16)*32]);
    }
    __syncthreads();
    bf16x8 af[4], bfr[4];
#pragma unroll
    for (int mt = 0; mt < 4; mt++) af[mt]  = *(const bf16x8*)&As[(wr*64 + mt*16 + l15)*32 + quad*8];
#pragma unroll
    for (int nt = 0; nt < 4; nt++) bfr[nt] = *(const bf16x8*)&Bs[(wc*64 + nt*16 + l15)*32 + quad*8];
#pragma unroll
    for (int mt = 0; mt < 4; mt++)
#pragma unroll
      for (int nt = 0; nt < 4; nt++)
        acc[mt][nt] = __builtin_amdgcn_mfma_f32_16x16x32_bf16(af[mt], bfr[nt], acc[mt][nt], 0, 0, 0);
    __syncthreads();
  }
#pragma unroll
  for (int mt = 0; mt < 4; mt++)
#pragma unroll
    for (int reg = 0; reg < 4; reg++) {
      int m = bm + wr*64 + mt*16 + quad*4 + reg;
      size_t rowoff = (size_t)m * N;
#pragma unroll
      for (int nt = 0; nt < 4; nt++) {
        int n = bn + wc*64 + nt*16 + l15;
        float v = acc[mt][nt][reg];
        if (GELU) v = 0.5f * v * (1.0f + erff(v * 0.70710678118f));
        if (ADDSRC) v += bf2f(addsrc[rowoff + n]);
        if (OUT_BF16) Cb[rowoff + n] = f2bf(v);
        else Cf[rowoff + n] = v;
      }
    }
}

// ---------------- per-head normalize q,k -> [B,H,N,DH] bf16 ----------------
__global__ __launch_bounds__(64) void k_headnorm(const u16* __restrict__ qkraw,
                                                 u16* __restrict__ qn, u16* __restrict__ kn) {
  int blk = blockIdx.x;
  int h = blk & (HEADS-1); int bi = blk >> 4;
  int b = bi >> 11, i = bi & (SEQ-1);
  int d = threadIdx.x;
  const u16* base = qkraw + (size_t)bi * (2*NDIM);
  float qv = bf2f(base[h*DH + d]);
  float kv = bf2f(base[NDIM + h*DH + d]);
  float qs = qv*qv, ks = kv*kv;
#pragma unroll
  for (int o = 32; o > 0; o >>= 1) { qs += __shfl_xor(qs, o); ks += __shfl_xor(ks, o); }
  size_t oidx = ((size_t)(b*HEADS + h) * SEQ + i) * DH + d;
  qn[oidx] = f2bf(qv / fmaxf(sqrtf(qs), 1e-12f));
  kn[oidx] = f2bf(kv / fmaxf(sqrtf(ks), 1e-12f));
}

// ---------------- MFMA attn (fp8 out, x256 scaled): swapped operands C[j][i] ----------------
// Block = 16 q-rows (i) x 2048 j. No max pass (|sim| <= 5.57). LDS bounce for coalesced stores.
__global__ __launch_bounds__(256) void k_attn(const u16* __restrict__ qb, const u16* __restrict__ kb,
                                              u8* __restrict__ attn, int bh0) {
  __shared__ __align__(16) u8 sim[16][2064];   // [i][j], +16B pad
  __shared__ float reds[4][16];
  int t = threadIdx.x;
  int w = t >> 6, L = t & 63;
  int quad = L >> 4, l15 = L & 15;
  int bh_local = blockIdx.x >> 7;              // 128 i-tiles per bh
  int bh = bh0 + bh_local;
  int i0 = (blockIdx.x & 127) * 16;
  // B-operand: Q row i = i0 + l15
  const u16* qrow = qb + ((size_t)bh*SEQ + i0 + l15)*DH + quad*8;
  bf16x8 b0 = *(const bf16x8*)qrow;
  bf16x8 b1 = *(const bf16x8*)(qrow + 32);
  const u16* kbase = kb + (size_t)bh*SEQ*DH;
  floatx4 acc[32];
  float s = 0.f;
#pragma unroll
  for (int tt = 0; tt < 32; tt++) {
    int j = w*512 + tt*16 + l15;               // A-operand row = j
    const u16* krow = kbase + (size_t)j*DH + quad*8;
    bf16x8 a0 = *(const bf16x8*)krow;
    bf16x8 a1 = *(const bf16x8*)(krow + 32);
    floatx4 c = (floatx4){0.f,0.f,0.f,0.f};
    c = __builtin_amdgcn_mfma_f32_16x16x32_bf16(a0, b0, c, 0, 0, 0);
    c = __builtin_amdgcn_mfma_f32_16x16x32_bf16(a1, b1, c, 0, 0, 0);
#pragma unroll
    for (int r = 0; r < 4; r++) { float e = exp2f(EXS * c[r]); c[r] = e; s += e; }
    acc[tt] = c;
  }
  // sum over j for fixed i=l15: reduce across quads, then across waves
  s += __shfl_xor(s, 16); s += __shfl_xor(s, 32);
  if (quad == 0) reds[w][l15] = s;
  __syncthreads();
  float inv = 256.0f / (reds[0][l15] + reds[1][l15] + reds[2][l15] + reds[3][l15]);
  // pack 4 consecutive j (regs) into uint32, write LDS [i][j]
#pragma unroll
  for (int tt = 0; tt < 32; tt++) {
    int p = pk4_e4m3(acc[tt][0]*inv, acc[tt][1]*inv, acc[tt][2]*inv, acc[tt][3]*inv);
    *(int*)&sim[l15][w*512 + tt*16 + quad*4] = p;
  }
  __syncthreads();
  // coalesced store: 16 rows x 2048 B (each thread copies 8 x 16B, stride 256B)
  int row = t >> 4, ch = t & 15;
  const uint4* srow = (const uint4*)&sim[row][0];
  uint4* drow = (uint4*)(attn + ((size_t)bh_local*SEQ + i0 + row)*SEQ);
#pragma unroll
  for (int k = 0; k < 8; k++) drow[ch + 16*k] = srow[ch + 16*k];
}

// ---------------- m0 init (fp8 0.5 = 0x30) ----------------
__global__ void k_minit8(unsigned int* __restrict__ m, unsigned int val, int nwords) {
  int i = blockIdx.x*256 + threadIdx.x; if (i < nwords) m[i] = val;
}

__global__ void k_zero(float* __restrict__ o, int n) {
  int i = blockIdx.x*256 + threadIdx.x; if (i < n) o[i] = 0.f;
}

// ---------------- fp8 MFMA mean-field step: m_out = mag(xf + (attn/256) @ m_in) ----------------
// attn fp8 [i][j] (x256), m fp8 transposed [bh][d][i]. Block: 128 i x 64 d, BK=32.
template<int LAST>
__global__ __launch_bounds__(256) void k_step(const u8* __restrict__ attn, const u8* __restrict__ mT_in,
                                              const float* __restrict__ xf, u8* __restrict__ mT_out,
                                              float* __restrict__ out, int bh0) {
  __shared__ __align__(16) u8 As[128*32];
  __shared__ __align__(16) u8 Bs[64*32];
  int t = threadIdx.x;
  int w = t >> 6, L = t & 63;
  int quad = L >> 4, l15 = L & 15;
  int bh_local = blockIdx.x >> 4;            // 16 i-tiles per bh
  int bh = bh0 + bh_local;
  int i0 = (blockIdx.x & 15) * 128;
  int b = bh >> 4, h = bh & (HEADS-1);
  const u8* abase = attn + (size_t)bh_local*SEQ*SEQ;
  const u8* mbase = mT_in + (size_t)bh*DH*SEQ;
  int arow = w*32 + (L >> 1);                // staging row for As (this wave)
  int acol = (L & 1) * 16;
  floatx4 acc[2][4];
#pragma unroll
  for (int i = 0; i < 2; i++)
#pragma unroll
    for (int j = 0; j < 4; j++) acc[i][j] = (floatx4){0.f,0.f,0.f,0.f};

  for (int j0 = 0; j0 < SEQ; j0 += 32) {
    GLD16(abase + (size_t)(i0 + arow)*SEQ + j0 + acol, &As[w*1024]);
    if (w < 2)
      GLD16(mbase + (size_t)(w*32 + (L >> 1))*SEQ + j0 + acol, &Bs[w*1024]);
    __syncthreads();
    i64 af[2], bfr[4];
#pragma unroll
    for (int mt = 0; mt < 2; mt++) af[mt]  = *(const i64*)&As[(w*32 + mt*16 + l15)*32 + quad*8];
#pragma unroll
    for (int nt = 0; nt < 4; nt++) bfr[nt] = *(const i64*)&Bs[(nt*16 + l15)*32 + quad*8];
#pragma unroll
    for (int mt = 0; mt < 2; mt++)
#pragma unroll
      for (int nt = 0; nt < 4; nt++)
        acc[mt][nt] = __builtin_amdgcn_mfma_f32_16x16x32_fp8_fp8(af[mt], bfr[nt], acc[mt][nt], 0, 0, 0);
    __syncthreads();
  }
  const float rs = 1.0f/256.0f;
#pragma unroll
  for (int mt = 0; mt < 2; mt++) {
    int ibase = i0 + w*32 + mt*16 + quad*4;
    float th[4][4]; float invr[4];
#pragma unroll
    for (int reg = 0; reg < 4; reg++) {
      size_t xoff = ((size_t)b*SEQ + ibase + reg)*NDIM + h*DH + l15;
      float s = 0.f;
#pragma unroll
      for (int nt = 0; nt < 4; nt++) {
        float v = acc[mt][nt][reg]*rs + xf[xoff + nt*16];
        th[nt][reg] = v; s += v*v;
      }
      s += __shfl_xor(s, 1); s += __shfl_xor(s, 2); s += __shfl_xor(s, 4); s += __shfl_xor(s, 8);
      float tt2 = 0.5f*(1.0f + sqrtf(1.0f + s * INV_SCALE2));
      invr[reg] = 1.0f/(2.0f*tt2);
    }
    if (LAST) {
#pragma unroll
      for (int reg = 0; reg < 4; reg++) {
        size_t ooff = ((size_t)b*SEQ + ibase + reg)*NDIM + h*DH + l15;
#pragma unroll
        for (int nt = 0; nt < 4; nt++) out[ooff + nt*16] = th[nt][reg]*invr[reg];
      }
    } else {
#pragma unroll
      for (int nt = 0; nt < 4; nt++) {
        int p = pk4_e4m3(th[nt][0]*invr[0], th[nt][1]*invr[1],
                         th[nt][2]*invr[2], th[nt][3]*invr[3]);
        *(int*)&mT_out[((size_t)bh*DH + nt*16 + l15)*SEQ + ibase] = p;
      }
    }
  }
}

extern "C" void kernel_launch(void* const* d_in, const int* in_sizes, int n_in,
                              void* d_out, int out_size, void* d_ws, size_t ws_size,
                              hipStream_t stream) {
  const void* x    = d_in[0];
  const void* w_qk = d_in[1];
  const void* w1   = d_in[2];
  const void* w2   = d_in[3];
  float* out = (float*)d_out;

  const size_t E = (size_t)BQ*SEQ*NDIM;     // 4,194,304
  const int NW_QK = 2*NDIM*NDIM;
  const int NW1   = 4*NDIM*NDIM;
  const int NW2   = 4*NDIM*NDIM;

  char* ws = (char*)d_ws;
  size_t off = 0;
  auto alloc = [&](size_t bytes) { void* p = ws + off; off += (bytes + 255) & ~255ull; return p; };
  int*  flag = (int*)alloc(256);
  u16*  xs  = (u16*)alloc(E*2);             // scaled-normalized x (bf16)
  u16*  qb  = (u16*)alloc(E*2);             // q normalized [B,H,N,DH] bf16
  u16*  kb  = (u16*)alloc(E*2);
  float* xf = (float*)alloc(E*4);           // external field fp32
  u8*   mT  = (u8*)alloc(E*2);              // two fp8 m-buffers [B,H,DH,N]
  u8*   mTa = mT;
  u8*   mTb = mT + E;

  char* S = ws + off;
  size_t availS = (ws_size > off) ? ws_size - off : 0;
  // S-region temporal plan: [wqkb|qkraw] -> [.|.|w1b|w2b|hbuf] -> [attn chunk fp8]
  u16* wqkb  = (u16*)(S);
  u16* qkraw = (u16*)(S + 4194304);
  u16* w1b   = (u16*)(S + 20971520);
  u16* w2b   = (u16*)(S + 29360128);
  u16* hbuf  = (u16*)(S + 37748736);
  u8*  attn  = (u8*)(S);
  u16* xb    = (u16*)mT;                     // alias (2E bytes): dead before k_minit8

  const int rcs[6] = {4096, 2048, 1024, 512, 256, 128};
  int RC = 0;
  for (int i = 0; i < 6; i++)
    if (37748736ull + (size_t)rcs[i]*4096*2 <= availS) { RC = rcs[i]; break; }
  const int chs[6] = {32, 16, 8, 4, 2, 1};
  int CH = 0;
  for (int i = 0; i < 6; i++)
    if ((size_t)chs[i]*SEQ*SEQ <= availS) { CH = chs[i]; break; }
  if (RC == 0 || CH == 0) {
    k_zero<<<(out_size+255)/256, 256, 0, stream>>>(out, out_size);
    return;
  }

  const int M = BQ*SEQ;  // 4096

  // dtype probe + canonical bf16 conversion
  k_flag0<<<1, 64, 0, stream>>>(flag);
  k_probe<<<256, 256, 0, stream>>>((const u16*)x, flag);
  k_convert<<<(int)(E/256), 256, 0, stream>>>(x, xb, flag, (int)E);
  k_convert<<<NW_QK/256, 256, 0, stream>>>(w_qk, wqkb, flag, NW_QK);
  k_convert<<<NW1/256, 256, 0, stream>>>(w1, w1b, flag, NW1);
  k_convert<<<NW2/256, 256, 0, stream>>>(w2, w2b, flag, NW2);

  k_norm_scale<<<M, 256, 0, stream>>>(xb, xs);
  { dim3 g(M/128, 2048/128); k_gemm<1,0,0><<<g, 256, 0, stream>>>(xs, wqkb, nullptr, qkraw, nullptr, M, 2048, 1024); }
  k_headnorm<<<M*HEADS, 64, 0, stream>>>(qkraw, qb, kb);

  for (int c = 0; c < M/RC; c++) {
    const u16* xsc = xs + (size_t)c*RC*NDIM;
    { dim3 g(RC/128, 4096/128); k_gemm<1,1,0><<<g, 256, 0, stream>>>(xsc, w1b, nullptr, hbuf, nullptr, RC, 4096, 1024); }
    { dim3 g(RC/128, 1024/128); k_gemm<0,0,1><<<g, 256, 0, stream>>>(hbuf, w2b, xf + (size_t)c*RC*NDIM, nullptr, xsc, RC, 1024, 4096); }
  }

  // m0 = 1/(2*t0) = 0.4853 -> e4m3 RNE -> 0.5 = 0x30
  k_minit8<<<(int)(E/4/256), 256, 0, stream>>>((unsigned int*)mTa, 0x30303030u, (int)(E/4));

  for (int c0 = 0; c0 < BQ*HEADS; c0 += CH) {
    k_attn<<<CH*128, 256, 0, stream>>>(qb, kb, attn, c0);
    for (int s = 0; s < NSTEPS; s++) {
      u8* src = (s & 1) ? mTb : mTa;
      u8* dst = (s & 1) ? mTa : mTb;
      if (s == NSTEPS-1)
        k_step<1><<<CH*16, 256, 0, stream>>>(attn, src, xf, nullptr, out, c0);
      else
        k_step<0><<<CH*16, 256, 0, stream>>>(attn, src, xf, dst, nullptr, c0);
    }
  }
}